// Round 8
// baseline (460.279 us; speedup 1.0000x reference)
//
#include <hip/hip_runtime.h>
#include <hip/hip_bf16.h>
#include <stdint.h>

#define HN 128      // hidden size
#define TSTEPS 250
#define ON 20       // output size
#define GK 700      // input size
#define TKK 28      // GEMM K tile (700 = 25*28 exactly)

typedef float v2f __attribute__((ext_vector_type(2)));

// VOP3P packed fp32 FMA. All sources must be VGPR PAIRS.
__device__ __forceinline__ void pkfma_lo(v2f& acc, v2f b2, v2f a2) {
    asm("v_pk_fma_f32 %0, %1, %2, %0 op_sel_hi:[1,0,1]"
        : "+v"(acc) : "v"(b2), "v"(a2));
}
__device__ __forceinline__ void pkfma_hi(v2f& acc, v2f b2, v2f a2) {
    asm("v_pk_fma_f32 %0, %1, %2, %0 op_sel:[0,1,0] op_sel_hi:[1,1,1]"
        : "+v"(acc) : "v"(b2), "v"(a2));
}

// wave-uniform lane broadcast (compile-time lane index)
__device__ __forceinline__ float rlane(float v, int k) {
    return __int_as_float(__builtin_amdgcn_readlane(__float_as_int(v), k));
}

// force a float4 to live in VGPRs (blocks remat-from-load)
#define PIN4(v) asm volatile("" : "+v"((v).x), "+v"((v).y), "+v"((v).z), "+v"((v).w))

// 64-long half-dot: weights float4[16] (static idx), spike slice wave-wide in
// sv (lane l holds s[l] of this half). Per k: 1 v_readlane + 1 v_fmac.
__device__ __forceinline__ float dot64(const float4 (&w)[16], float sv) {
    float q0 = 0.f, q1 = 0.f, q2 = 0.f, q3 = 0.f;
#pragma unroll
    for (int m = 0; m < 16; ++m) {
        q0 = fmaf(rlane(sv, 4 * m + 0), w[m].x, q0);
        q1 = fmaf(rlane(sv, 4 * m + 1), w[m].y, q1);
        q2 = fmaf(rlane(sv, 4 * m + 2), w[m].z, q2);
        q3 = fmaf(rlane(sv, 4 * m + 3), w[m].w, q3);
    }
    return (q0 + q1) + (q2 + q3);
}

// ---------------------------------------------------------------------------
// Phase A: in1_ff[bt,h] = X[bt,:] . W_ih1[h,:] + b_ih1[h]
// M=64000, N=128, K=700. Double-buffered LDS, global->reg prefetch, pk_fma.
// ---------------------------------------------------------------------------
__global__ __launch_bounds__(256) void ff_gemm(const float* __restrict__ X,
                                               const float* __restrict__ W,
                                               const float* __restrict__ bias,
                                               float* __restrict__ out) {
    __shared__ __align__(16) float Xs[2][TKK][HN];
    __shared__ __align__(16) float Ws[2][TKK][HN];
    const int tid = threadIdx.x;
    const int tx = tid & 15;
    const int ty = tid >> 4;
    const int m0 = blockIdx.x * 128;

    v2f acc2[8][4];
#pragma unroll
    for (int i = 0; i < 8; ++i)
#pragma unroll
        for (int n = 0; n < 4; ++n) acc2[i][n] = (v2f){0.f, 0.f};

    float4 xr[4], wrg[4];

#define LOADT(k0)                                                              \
    {                                                                          \
        _Pragma("unroll")                                                      \
        for (int rr = 0; rr < 4; ++rr) {                                       \
            const int idx = tid + rr * 256;                                    \
            if (idx < 896) {                                                   \
                const int kb = idx >> 7, r = idx & 127;                        \
                xr[rr]  = *(const float4*)&X[(size_t)(m0 + r) * GK + (k0) + kb * 4]; \
                wrg[rr] = *(const float4*)&W[(size_t)r * GK + (k0) + kb * 4];  \
            }                                                                  \
        }                                                                      \
    }
#define STORET(buf)                                                            \
    {                                                                          \
        _Pragma("unroll")                                                      \
        for (int rr = 0; rr < 4; ++rr) {                                       \
            const int idx = tid + rr * 256;                                    \
            if (idx < 896) {                                                   \
                const int kb = idx >> 7, r = idx & 127;                        \
                Xs[buf][kb * 4 + 0][r] = xr[rr].x;                             \
                Xs[buf][kb * 4 + 1][r] = xr[rr].y;                             \
                Xs[buf][kb * 4 + 2][r] = xr[rr].z;                             \
                Xs[buf][kb * 4 + 3][r] = xr[rr].w;                             \
                Ws[buf][kb * 4 + 0][r] = wrg[rr].x;                            \
                Ws[buf][kb * 4 + 1][r] = wrg[rr].y;                            \
                Ws[buf][kb * 4 + 2][r] = wrg[rr].z;                            \
                Ws[buf][kb * 4 + 3][r] = wrg[rr].w;                            \
            }                                                                  \
        }                                                                      \
    }

    LOADT(0);
    STORET(0);
    __syncthreads();
    int cur = 0;
    for (int t = 0; t < 25; ++t) {
        if (t + 1 < 25) LOADT((t + 1) * TKK);
#pragma unroll
        for (int k = 0; k < TKK; ++k) {
            const float4 A0 = *(const float4*)&Xs[cur][k][ty * 8];
            const float4 A1 = *(const float4*)&Xs[cur][k][ty * 8 + 4];
            const float4 B0 = *(const float4*)&Ws[cur][k][tx * 8];
            const float4 B1 = *(const float4*)&Ws[cur][k][tx * 8 + 4];
            v2f a2[4], b2[4];
            a2[0] = (v2f){A0.x, A0.y}; a2[1] = (v2f){A0.z, A0.w};
            a2[2] = (v2f){A1.x, A1.y}; a2[3] = (v2f){A1.z, A1.w};
            b2[0] = (v2f){B0.x, B0.y}; b2[1] = (v2f){B0.z, B0.w};
            b2[2] = (v2f){B1.x, B1.y}; b2[3] = (v2f){B1.z, B1.w};
#pragma unroll
            for (int ip = 0; ip < 4; ++ip)
#pragma unroll
                for (int n = 0; n < 4; ++n) {
                    pkfma_lo(acc2[2 * ip][n],     b2[n], a2[ip]);
                    pkfma_hi(acc2[2 * ip + 1][n], b2[n], a2[ip]);
                }
        }
        if (t + 1 < 25) STORET(cur ^ 1);
        __syncthreads();
        cur ^= 1;
    }

    const float4 bv0 = *(const float4*)&bias[tx * 8];
    const float4 bv1 = *(const float4*)&bias[tx * 8 + 4];
#pragma unroll
    for (int i = 0; i < 8; ++i) {
        const size_t row = (size_t)(m0 + ty * 8 + i);
        float4 v0, v1;
        v0.x = acc2[i][0].x + bv0.x; v0.y = acc2[i][0].y + bv0.y;
        v0.z = acc2[i][1].x + bv0.z; v0.w = acc2[i][1].y + bv0.w;
        v1.x = acc2[i][2].x + bv1.x; v1.y = acc2[i][2].y + bv1.y;
        v1.z = acc2[i][3].x + bv1.z; v1.w = acc2[i][3].y + bv1.w;
        *(float4*)&out[row * HN + tx * 8]     = v0;
        *(float4*)&out[row * HN + tx * 8 + 4] = v1;
    }
#undef LOADT
#undef STORET
}

// ---------------------------------------------------------------------------
// Phase B: split-k readlane pipeline. 1024 thr (16 waves) per batch row.
// Each heavy thread owns HALF a weight row (16 float4 = 64 VGPRs -> within
// the allocator's proven ~88-VGPR comfort zone, so weights stay resident).
// Roles (one wave of each heavy role per SIMD):
//   waves 0-3 : S1   -> s1(i)        waves 4-7 : B  -> pB(i-1)
//   waves 8-11: C+L2 -> s2(i-2)      waves 12-13: RO -> rdot(i-3) partials
//   wave 14   : OM   -> om/softmax(i-4)      wave 15: idle
// Slot = [phase A: half-dots, half-1 publishes partial] bar
//        [phase B: half-0 combines + LIF + spike publish] bar
// ---------------------------------------------------------------------------
__global__ __launch_bounds__(1024)
__attribute__((amdgpu_waves_per_eu(4, 4)))
void srnn_pipe6(
    const float* __restrict__ ff,
    const float* __restrict__ W_h1h1, const float* __restrict__ b_h1h1,
    const float* __restrict__ W_h1h2, const float* __restrict__ b_h1h2,
    const float* __restrict__ W_h2h2, const float* __restrict__ b_h2h2,
    const float* __restrict__ W_h2o,  const float* __restrict__ b_h2o,
    const float* __restrict__ tau_adp_h1, const float* __restrict__ tau_adp_h2,
    const float* __restrict__ tau_m_h1,   const float* __restrict__ tau_m_h2,
    const float* __restrict__ tau_m_o,
    const float* __restrict__ h1m0, const float* __restrict__ h2m0,
    const float* __restrict__ om0,
    float* __restrict__ out) {
    const int b    = blockIdx.x;
    const int tid  = threadIdx.x;
    const int lane = tid & 63;

    __shared__ __align__(16) float s1f[2][HN];
    __shared__ __align__(16) float s2f[2][HN];
    __shared__ __align__(16) float pBbuf[2][HN];
    __shared__ __align__(16) float partA[HN];
    __shared__ __align__(16) float partB[HN];
    __shared__ __align__(16) float partC[HN];
    __shared__ float ro_part[2][2][32];

    if (tid < HN) {
        s1f[0][tid] = 0.f; s1f[1][tid] = 0.f;
        s2f[0][tid] = 0.f; s2f[1][tid] = 0.f;
    }
    __syncthreads();

    if (tid < 256) {
        // ================= S1: layer-1 LIF =================
        const int r = tid, j = r & 127, half = r >> 7;
        const float4* Wv = (const float4*)W_h1h1 + j * 32 + half * 16;
        float4 wA[16];
#pragma unroll
        for (int m = 0; m < 16; ++m) { wA[m] = Wv[m]; PIN4(wA[m]); }
        float h1m = 0.f, a1 = 0.f, r1 = 0.f, bias1 = 0.f;
        float b1 = 0.01f, s1p = 0.f, ff_c = 0.f, ff_n = 0.f;
        const float* ffp = ff + (size_t)b * TSTEPS * HN + j;
        if (half == 0) {
            h1m = h1m0[b * HN + j];
            a1 = expf(-1.f / tau_m_h1[j]);
            r1 = expf(-1.f / tau_adp_h1[j]);
            bias1 = b_h1h1[j];
            ff_c = ffp[0];
            ff_n = ffp[HN];
        }
        for (int i = 0; i < TSTEPS + 4; ++i) {
            float pA = 0.f;
            if (i < TSTEPS) {
                const float sv = s1f[(i + 1) & 1][half * 64 + lane];  // s1(i-1)
                pA = dot64(wA, sv);
                if (half) partA[j] = pA;
            }
            __syncthreads();
            if (i < TSTEPS && half == 0) {
                const float ff_2 = (i + 2 < TSTEPS) ? ffp[(size_t)(i + 2) * HN] : 0.f;
                const float in1 = ff_c + bias1 + pA + partA[j];
                b1 = r1 * b1 + (1.f - r1) * s1p;
                const float Bth = 0.01f + 1.8f * b1;
                h1m = h1m * a1 + (1.f - a1) * in1 - Bth * s1p;
                s1p = (h1m - Bth > 0.f) ? 1.f : 0.f;
                s1f[i & 1][j] = s1p;
                ff_c = ff_n; ff_n = ff_2;
            }
            __syncthreads();
        }
    } else if (tid < 512) {
        // ================= B: pB(i-1) = W_h1h2 . s1(i-1) =================
        const int r = tid - 256, j = r & 127, half = r >> 7;
        const float4* Wv = (const float4*)W_h1h2 + j * 32 + half * 16;
        float4 wB[16];
#pragma unroll
        for (int m = 0; m < 16; ++m) { wB[m] = Wv[m]; PIN4(wB[m]); }
        for (int i = 0; i < TSTEPS + 4; ++i) {
            float pB = 0.f;
            if (i >= 1 && i <= TSTEPS) {
                const float sv = s1f[(i - 1) & 1][half * 64 + lane];
                pB = dot64(wB, sv);
                if (half) partB[j] = pB;
            }
            __syncthreads();
            if (i >= 1 && i <= TSTEPS && half == 0)
                pBbuf[(i - 1) & 1][j] = pB + partB[j];
            __syncthreads();
        }
    } else if (tid < 768) {
        // ================= C + LIF2: s2(i-2) =================
        const int r = tid - 512, j = r & 127, half = r >> 7;
        const float4* Wv = (const float4*)W_h2h2 + j * 32 + half * 16;
        float4 wC[16];
#pragma unroll
        for (int m = 0; m < 16; ++m) { wC[m] = Wv[m]; PIN4(wC[m]); }
        float h2m = 0.f, a2 = 0.f, r2 = 0.f, bias2 = 0.f;
        float b2v = 0.01f, s2p = 0.f;
        if (half == 0) {
            h2m = h2m0[b * HN + j];
            a2 = expf(-1.f / tau_m_h2[j]);
            r2 = expf(-1.f / tau_adp_h2[j]);
            bias2 = b_h1h2[j] + b_h2h2[j];
        }
        for (int i = 0; i < TSTEPS + 4; ++i) {
            const int k2 = i - 2;
            float pC = 0.f;
            if (i >= 2 && i <= TSTEPS + 1) {
                const float sv = s2f[(k2 + 1) & 1][half * 64 + lane];  // s2(k2-1)
                pC = dot64(wC, sv);
                if (half) partC[j] = pC;
            }
            __syncthreads();
            if (i >= 2 && i <= TSTEPS + 1 && half == 0) {
                const float in2 = pBbuf[k2 & 1][j] + pC + partC[j] + bias2;
                b2v = r2 * b2v + (1.f - r2) * s2p;
                const float Bth = 0.01f + 1.8f * b2v;
                h2m = h2m * a2 + (1.f - a2) * in2 - Bth * s2p;
                s2p = (h2m - Bth > 0.f) ? 1.f : 0.f;
                s2f[k2 & 1][j] = s2p;
            }
            __syncthreads();
        }
    } else if (tid < 896) {
        // ================= RO: rdot(i-3) partials =================
        const int r = tid - 768, half = r >> 6, o = lane;   // active o < ON
        const float4* Wv = (const float4*)W_h2o + (size_t)((o < ON) ? o : 0) * 32 + half * 16;
        float4 wO[16];
#pragma unroll
        for (int m = 0; m < 16; ++m) { wO[m] = Wv[m]; PIN4(wO[m]); }
        for (int i = 0; i < TSTEPS + 4; ++i) {
            if (i >= 3 && i <= TSTEPS + 2) {
                const int k3 = i - 3;
                const float sv = s2f[k3 & 1][half * 64 + lane];
                const float rr = dot64(wO, sv);
                if (o < ON) ro_part[k3 & 1][half][o] = rr;
            }
            __syncthreads();
            __syncthreads();
        }
    } else if (tid < 960) {
        // ================= OM: leaky readout + softmax accumulate ==========
        const int o = lane;
        float om = 0.f, ao = 0.f, bo = 0.f, acc = 0.f;
        if (o < ON) {
            om = om0[b * ON + o];
            ao = expf(-1.f / tau_m_o[o]);
            bo = b_h2o[o];
        }
        for (int i = 0; i < TSTEPS + 4; ++i) {
            if (i >= 4) {
                const int k4 = i - 4;
                if (o < ON)
                    om = om * ao + (1.f - ao) *
                         (ro_part[k4 & 1][0][o] + ro_part[k4 & 1][1][o] + bo);
                float mx = (o < ON) ? om : -3.4e38f;
#pragma unroll
                for (int m = 16; m >= 1; m >>= 1)
                    mx = fmaxf(mx, __shfl_xor(mx, m));
                float e = (o < ON) ? __expf(om - mx) : 0.f;
                float den = e;
#pragma unroll
                for (int m = 16; m >= 1; m >>= 1)
                    den += __shfl_xor(den, m);
                if (o < ON && k4 > 10) acc += e / den;
            }
            __syncthreads();
            __syncthreads();
        }
        if (o < ON) out[b * ON + o] = acc;
    } else {
        // ================= idle wave: barrier balance =================
        for (int i = 0; i < TSTEPS + 4; ++i) {
            __syncthreads();
            __syncthreads();
        }
    }
}

// ---------------------------------------------------------------------------
// Phase C: A_norm = sum|W_h1h1| + sum|W_h2h2|  -> out[5120]
// ---------------------------------------------------------------------------
__global__ void anorm_kernel(const float* __restrict__ W1,
                             const float* __restrict__ W2,
                             float* __restrict__ out) {
    __shared__ float red[256];
    float s = 0.f;
    for (int i = threadIdx.x; i < HN * HN; i += 256)
        s += fabsf(W1[i]) + fabsf(W2[i]);
    red[threadIdx.x] = s;
    __syncthreads();
    for (int off = 128; off > 0; off >>= 1) {
        if (threadIdx.x < off) red[threadIdx.x] += red[threadIdx.x + off];
        __syncthreads();
    }
    if (threadIdx.x == 0) out[256 * ON] = red[0];
}

extern "C" void kernel_launch(void* const* d_in, const int* in_sizes, int n_in,
                              void* d_out, int out_size, void* d_ws, size_t ws_size,
                              hipStream_t stream) {
    const float* input      = (const float*)d_in[0];
    // d_in[1], d_in[2]: A1_mask/A2_mask -- all-ones, unused by reference math
    const float* W_ih1      = (const float*)d_in[3];
    const float* b_ih1      = (const float*)d_in[4];
    const float* W_h1h1     = (const float*)d_in[5];
    const float* b_h1h1     = (const float*)d_in[6];
    const float* W_h1h2     = (const float*)d_in[7];
    const float* b_h1h2     = (const float*)d_in[8];
    const float* W_h2h2     = (const float*)d_in[9];
    const float* b_h2h2     = (const float*)d_in[10];
    const float* W_h2o      = (const float*)d_in[11];
    const float* b_h2o      = (const float*)d_in[12];
    const float* tau_adp_h1 = (const float*)d_in[13];
    const float* tau_adp_h2 = (const float*)d_in[14];
    const float* tau_m_h1   = (const float*)d_in[15];
    const float* tau_m_h2   = (const float*)d_in[16];
    const float* tau_m_o    = (const float*)d_in[17];
    const float* h1m0       = (const float*)d_in[18];
    const float* h2m0       = (const float*)d_in[19];
    const float* om0        = (const float*)d_in[20];

    float* out   = (float*)d_out;
    float* ffbuf = (float*)d_ws;   // 256*250*128*4 = 32.768 MB

    anorm_kernel<<<1, 256, 0, stream>>>(W_h1h1, W_h2h2, out);
    ff_gemm<<<500, 256, 0, stream>>>(input, W_ih1, b_ih1, ffbuf);
    srnn_pipe6<<<256, 1024, 0, stream>>>(ffbuf, W_h1h1, b_h1h1, W_h1h2, b_h1h2,
                                         W_h2h2, b_h2h2, W_h2o, b_h2o,
                                         tau_adp_h1, tau_adp_h2,
                                         tau_m_h1, tau_m_h2, tau_m_o,
                                         h1m0, h2m0, om0, out);
}

// Round 9
// 394.399 us; speedup vs baseline: 1.1670x; 1.1670x over previous
//
#include <hip/hip_runtime.h>
#include <hip/hip_bf16.h>
#include <stdint.h>

#define HN 128      // hidden size
#define TSTEPS 250
#define ON 20       // output size
#define GK 700      // input size
#define TKK 28      // GEMM K tile (700 = 25*28 exactly)

typedef float v2f __attribute__((ext_vector_type(2)));
typedef _Float16 h2 __attribute__((ext_vector_type(2)));

// VOP3P packed fp32 FMA (GEMM). All sources must be VGPR PAIRS.
__device__ __forceinline__ void pkfma_lo(v2f& acc, v2f b2, v2f a2) {
    asm("v_pk_fma_f32 %0, %1, %2, %0 op_sel_hi:[1,0,1]"
        : "+v"(acc) : "v"(b2), "v"(a2));
}
__device__ __forceinline__ void pkfma_hi(v2f& acc, v2f b2, v2f a2) {
    asm("v_pk_fma_f32 %0, %1, %2, %0 op_sel:[0,1,0] op_sel_hi:[1,1,1]"
        : "+v"(acc) : "v"(b2), "v"(a2));
}

__device__ __forceinline__ h2 bch_u(uint32_t u) { return __builtin_bit_cast(h2, u); }
__device__ __forceinline__ h2 bch_f(float f)    { return __builtin_bit_cast(h2, f); }
__device__ __forceinline__ float fdot2(h2 a, h2 b, float c) {
    return __builtin_amdgcn_fdot2(a, b, c, false);
}
__device__ __forceinline__ float pack2(float x, float y) {
    h2 p; p.x = (_Float16)x; p.y = (_Float16)y;
    return __builtin_bit_cast(float, p);
}

// 128-dot for TWO output rows (jlo, jhi) against the wave-uniform spike
// vector held in sv[16] (128 f16). Weights k-major packed: WP[t][j] holds
// w[j][8t..8t+7]. 32 conflict-free ds_read_b128 + 128 v_dot2 per call.
__device__ __forceinline__ void mv2(const float4 (&WP)[16][HN], const uint4 (&sv)[16],
                                    int jlo, int jhi, float& olo, float& ohi) {
    float a0 = 0.f, a1 = 0.f, a2 = 0.f, a3 = 0.f;
    float b0 = 0.f, b1 = 0.f, b2 = 0.f, b3 = 0.f;
#pragma unroll
    for (int t = 0; t < 16; ++t) {
        const float4 wl = WP[t][jlo];
        const float4 wh = WP[t][jhi];
        const uint4  s  = sv[t];
        const h2 s0 = bch_u(s.x), s1 = bch_u(s.y), s2 = bch_u(s.z), s3 = bch_u(s.w);
        a0 = fdot2(bch_f(wl.x), s0, a0); a1 = fdot2(bch_f(wl.y), s1, a1);
        a2 = fdot2(bch_f(wl.z), s2, a2); a3 = fdot2(bch_f(wl.w), s3, a3);
        b0 = fdot2(bch_f(wh.x), s0, b0); b1 = fdot2(bch_f(wh.y), s1, b1);
        b2 = fdot2(bch_f(wh.z), s2, b2); b3 = fdot2(bch_f(wh.w), s3, b3);
    }
    olo = (a0 + a1) + (a2 + a3);
    ohi = (b0 + b1) + (b2 + b3);
}

// single-row variant (readout rows)
__device__ __forceinline__ float mv1(const float4 (&WP)[16][32], const uint4 (&sv)[16],
                                     int j) {
    float a0 = 0.f, a1 = 0.f, a2 = 0.f, a3 = 0.f;
#pragma unroll
    for (int t = 0; t < 16; ++t) {
        const float4 wl = WP[t][j];
        const uint4  s  = sv[t];
        a0 = fdot2(bch_f(wl.x), bch_u(s.x), a0);
        a1 = fdot2(bch_f(wl.y), bch_u(s.y), a1);
        a2 = fdot2(bch_f(wl.z), bch_u(s.z), a2);
        a3 = fdot2(bch_f(wl.w), bch_u(s.w), a3);
    }
    return (a0 + a1) + (a2 + a3);
}

#define LOADSPIKES(arr, buf, sv)                                               \
    {                                                                          \
        const uint4* _p = (const uint4*)&arr[buf][0];                          \
        _Pragma("unroll") for (int _t = 0; _t < 16; ++_t) sv[_t] = _p[_t];     \
    }

// ---------------------------------------------------------------------------
// Phase A: in1_ff[bt,h] = X[bt,:] . W_ih1[h,:] + b_ih1[h]  (fp32, unchanged)
// ---------------------------------------------------------------------------
__global__ __launch_bounds__(256) void ff_gemm(const float* __restrict__ X,
                                               const float* __restrict__ W,
                                               const float* __restrict__ bias,
                                               float* __restrict__ out) {
    __shared__ __align__(16) float Xs[2][TKK][HN];
    __shared__ __align__(16) float Ws[2][TKK][HN];
    const int tid = threadIdx.x;
    const int tx = tid & 15;
    const int ty = tid >> 4;
    const int m0 = blockIdx.x * 128;

    v2f acc2[8][4];
#pragma unroll
    for (int i = 0; i < 8; ++i)
#pragma unroll
        for (int n = 0; n < 4; ++n) acc2[i][n] = (v2f){0.f, 0.f};

    float4 xr[4], wrg[4];

#define LOADT(k0)                                                              \
    {                                                                          \
        _Pragma("unroll")                                                      \
        for (int rr = 0; rr < 4; ++rr) {                                       \
            const int idx = tid + rr * 256;                                    \
            if (idx < 896) {                                                   \
                const int kb = idx >> 7, r = idx & 127;                        \
                xr[rr]  = *(const float4*)&X[(size_t)(m0 + r) * GK + (k0) + kb * 4]; \
                wrg[rr] = *(const float4*)&W[(size_t)r * GK + (k0) + kb * 4];  \
            }                                                                  \
        }                                                                      \
    }
#define STORET(buf)                                                            \
    {                                                                          \
        _Pragma("unroll")                                                      \
        for (int rr = 0; rr < 4; ++rr) {                                       \
            const int idx = tid + rr * 256;                                    \
            if (idx < 896) {                                                   \
                const int kb = idx >> 7, r = idx & 127;                        \
                Xs[buf][kb * 4 + 0][r] = xr[rr].x;                             \
                Xs[buf][kb * 4 + 1][r] = xr[rr].y;                             \
                Xs[buf][kb * 4 + 2][r] = xr[rr].z;                             \
                Xs[buf][kb * 4 + 3][r] = xr[rr].w;                             \
                Ws[buf][kb * 4 + 0][r] = wrg[rr].x;                            \
                Ws[buf][kb * 4 + 1][r] = wrg[rr].y;                            \
                Ws[buf][kb * 4 + 2][r] = wrg[rr].z;                            \
                Ws[buf][kb * 4 + 3][r] = wrg[rr].w;                            \
            }                                                                  \
        }                                                                      \
    }

    LOADT(0);
    STORET(0);
    __syncthreads();
    int cur = 0;
    for (int t = 0; t < 25; ++t) {
        if (t + 1 < 25) LOADT((t + 1) * TKK);
#pragma unroll
        for (int k = 0; k < TKK; ++k) {
            const float4 A0 = *(const float4*)&Xs[cur][k][ty * 8];
            const float4 A1 = *(const float4*)&Xs[cur][k][ty * 8 + 4];
            const float4 B0 = *(const float4*)&Ws[cur][k][tx * 8];
            const float4 B1 = *(const float4*)&Ws[cur][k][tx * 8 + 4];
            v2f a2[4], b2[4];
            a2[0] = (v2f){A0.x, A0.y}; a2[1] = (v2f){A0.z, A0.w};
            a2[2] = (v2f){A1.x, A1.y}; a2[3] = (v2f){A1.z, A1.w};
            b2[0] = (v2f){B0.x, B0.y}; b2[1] = (v2f){B0.z, B0.w};
            b2[2] = (v2f){B1.x, B1.y}; b2[3] = (v2f){B1.z, B1.w};
#pragma unroll
            for (int ip = 0; ip < 4; ++ip)
#pragma unroll
                for (int n = 0; n < 4; ++n) {
                    pkfma_lo(acc2[2 * ip][n],     b2[n], a2[ip]);
                    pkfma_hi(acc2[2 * ip + 1][n], b2[n], a2[ip]);
                }
        }
        if (t + 1 < 25) STORET(cur ^ 1);
        __syncthreads();
        cur ^= 1;
    }

    const float4 bv0 = *(const float4*)&bias[tx * 8];
    const float4 bv1 = *(const float4*)&bias[tx * 8 + 4];
#pragma unroll
    for (int i = 0; i < 8; ++i) {
        const size_t row = (size_t)(m0 + ty * 8 + i);
        float4 v0, v1;
        v0.x = acc2[i][0].x + bv0.x; v0.y = acc2[i][0].y + bv0.y;
        v0.z = acc2[i][1].x + bv0.z; v0.w = acc2[i][1].y + bv0.w;
        v1.x = acc2[i][2].x + bv1.x; v1.y = acc2[i][2].y + bv1.y;
        v1.z = acc2[i][3].x + bv1.z; v1.w = acc2[i][3].y + bv1.w;
        *(float4*)&out[row * HN + tx * 8]     = v0;
        *(float4*)&out[row * HN + tx * 8 + 4] = v1;
    }
#undef LOADT
#undef STORET
}

// ---------------------------------------------------------------------------
// Phase B: f16-LDS dot2 pipeline. One WG (512 thr, 8 waves) per batch row.
// All weights converted to f16 once and staged k-major-packed in LDS
// (A+B+C 96 KB + O 8 KB): ds_read_b128 across lanes is contiguous ->
// conflict-free; spike vector is 128 f16 read wave-uniform (broadcast).
// Matvec = 128 v_dot2_f32_f16 per wave (2 rows/lane). Roles (slot i, one
// barrier each, r5-verified offsets):
//   w0: S1 -> s1(i)   w1: B -> pB(i-1)   w2: C+L2 -> s2(i-2)
//   w3: RO -> rdot(i-3)   w4: OM -> om/softmax(i-4)   w5-7: idle
// ---------------------------------------------------------------------------
__global__ __launch_bounds__(512) void srnn_pipe7(
    const float* __restrict__ ff,
    const float* __restrict__ W_h1h1, const float* __restrict__ b_h1h1,
    const float* __restrict__ W_h1h2, const float* __restrict__ b_h1h2,
    const float* __restrict__ W_h2h2, const float* __restrict__ b_h2h2,
    const float* __restrict__ W_h2o,  const float* __restrict__ b_h2o,
    const float* __restrict__ tau_adp_h1, const float* __restrict__ tau_adp_h2,
    const float* __restrict__ tau_m_h1,   const float* __restrict__ tau_m_h2,
    const float* __restrict__ tau_m_o,
    const float* __restrict__ h1m0, const float* __restrict__ h2m0,
    const float* __restrict__ om0,
    float* __restrict__ out) {
    const int b    = blockIdx.x;
    const int tid  = threadIdx.x;
    const int w    = tid >> 6;
    const int lane = tid & 63;

    __shared__ float4 WPA[16][HN];   // 32 KB  W_h1h1 f16 k-major
    __shared__ float4 WPB[16][HN];   // 32 KB  W_h1h2
    __shared__ float4 WPC[16][HN];   // 32 KB  W_h2h2
    __shared__ float4 WPO[16][32];   //  8 KB  W_h2o (rows 0..19, rest zero)
    __shared__ _Float16 s1h[2][HN];
    __shared__ _Float16 s2h[2][HN];
    __shared__ float pBbuf[2][HN];
    __shared__ float rdot_lds[2][32];

    // ---- stage weights fp32->f16 (one time) ----
#pragma unroll
    for (int e = tid; e < 2048; e += 512) {
        const int t = e >> 7, j = e & 127;
        {
            const float* s = W_h1h1 + j * HN + t * 8;
            float4 x0 = *(const float4*)s, x1 = *(const float4*)(s + 4);
            float4 d; d.x = pack2(x0.x, x0.y); d.y = pack2(x0.z, x0.w);
            d.z = pack2(x1.x, x1.y); d.w = pack2(x1.z, x1.w);
            WPA[t][j] = d;
        }
        {
            const float* s = W_h1h2 + j * HN + t * 8;
            float4 x0 = *(const float4*)s, x1 = *(const float4*)(s + 4);
            float4 d; d.x = pack2(x0.x, x0.y); d.y = pack2(x0.z, x0.w);
            d.z = pack2(x1.x, x1.y); d.w = pack2(x1.z, x1.w);
            WPB[t][j] = d;
        }
        {
            const float* s = W_h2h2 + j * HN + t * 8;
            float4 x0 = *(const float4*)s, x1 = *(const float4*)(s + 4);
            float4 d; d.x = pack2(x0.x, x0.y); d.y = pack2(x0.z, x0.w);
            d.z = pack2(x1.x, x1.y); d.w = pack2(x1.z, x1.w);
            WPC[t][j] = d;
        }
    }
    {
        const int t = tid >> 5, j = tid & 31;   // 512 = 16*32 exactly
        float4 d = {0.f, 0.f, 0.f, 0.f};
        if (j < ON) {
            const float* s = W_h2o + j * HN + t * 8;
            float4 x0 = *(const float4*)s, x1 = *(const float4*)(s + 4);
            d.x = pack2(x0.x, x0.y); d.y = pack2(x0.z, x0.w);
            d.z = pack2(x1.x, x1.y); d.w = pack2(x1.z, x1.w);
        }
        WPO[t][j] = d;
    }
    if (tid < HN) {
        s1h[0][tid] = (_Float16)0; s1h[1][tid] = (_Float16)0;
        s2h[0][tid] = (_Float16)0; s2h[1][tid] = (_Float16)0;
    }
    __syncthreads();

    if (w == 0) {
        // ================= S1: layer-1 LIF (j = lane, lane+64) ============
        const int jl = lane, jh = lane + 64;
        float h1m_l = h1m0[b * HN + jl],        h1m_h = h1m0[b * HN + jh];
        const float a1_l = expf(-1.f / tau_m_h1[jl]),   a1_h = expf(-1.f / tau_m_h1[jh]);
        const float r1_l = expf(-1.f / tau_adp_h1[jl]), r1_h = expf(-1.f / tau_adp_h1[jh]);
        const float bi_l = b_h1h1[jl],          bi_h = b_h1h1[jh];
        float b1_l = 0.01f, b1_h = 0.01f, s1_l = 0.f, s1_h = 0.f;
        const float* fpl = ff + (size_t)b * TSTEPS * HN + jl;
        const float* fph = ff + (size_t)b * TSTEPS * HN + jh;
        float fc_l = fpl[0], fn_l = fpl[HN];
        float fc_h = fph[0], fn_h = fph[HN];
        for (int i = 0; i < TSTEPS + 4; ++i) {
            if (i < TSTEPS) {
                const float f2l = (i + 2 < TSTEPS) ? fpl[(size_t)(i + 2) * HN] : 0.f;
                const float f2h = (i + 2 < TSTEPS) ? fph[(size_t)(i + 2) * HN] : 0.f;
                uint4 sv[16];
                LOADSPIKES(s1h, (i + 1) & 1, sv);          // s1(i-1)
                float pAl, pAh;
                mv2(WPA, sv, jl, jh, pAl, pAh);
                b1_l = r1_l * b1_l + (1.f - r1_l) * s1_l;
                b1_h = r1_h * b1_h + (1.f - r1_h) * s1_h;
                const float Btl = 0.01f + 1.8f * b1_l;
                const float Bth = 0.01f + 1.8f * b1_h;
                h1m_l = h1m_l * a1_l + (1.f - a1_l) * (fc_l + bi_l + pAl) - Btl * s1_l;
                h1m_h = h1m_h * a1_h + (1.f - a1_h) * (fc_h + bi_h + pAh) - Bth * s1_h;
                s1_l = (h1m_l - Btl > 0.f) ? 1.f : 0.f;
                s1_h = (h1m_h - Bth > 0.f) ? 1.f : 0.f;
                s1h[i & 1][jl] = (_Float16)s1_l;
                s1h[i & 1][jh] = (_Float16)s1_h;
                fc_l = fn_l; fn_l = f2l;
                fc_h = fn_h; fn_h = f2h;
            }
            __syncthreads();
        }
    } else if (w == 1) {
        // ================= B: pB(i-1) = W_h1h2 . s1(i-1) =================
        const int jl = lane, jh = lane + 64;
        for (int i = 0; i < TSTEPS + 4; ++i) {
            if (i >= 1 && i <= TSTEPS) {
                uint4 sv[16];
                LOADSPIKES(s1h, (i - 1) & 1, sv);
                float pl, ph;
                mv2(WPB, sv, jl, jh, pl, ph);
                pBbuf[(i - 1) & 1][jl] = pl;
                pBbuf[(i - 1) & 1][jh] = ph;
            }
            __syncthreads();
        }
    } else if (w == 2) {
        // ================= C + LIF2: s2(i-2) =================
        const int jl = lane, jh = lane + 64;
        float h2m_l = h2m0[b * HN + jl],        h2m_h = h2m0[b * HN + jh];
        const float a2_l = expf(-1.f / tau_m_h2[jl]),   a2_h = expf(-1.f / tau_m_h2[jh]);
        const float r2_l = expf(-1.f / tau_adp_h2[jl]), r2_h = expf(-1.f / tau_adp_h2[jh]);
        const float bi_l = b_h1h2[jl] + b_h2h2[jl];
        const float bi_h = b_h1h2[jh] + b_h2h2[jh];
        float b2_l = 0.01f, b2_h = 0.01f, s2_l = 0.f, s2_h = 0.f;
        for (int i = 0; i < TSTEPS + 4; ++i) {
            if (i >= 2 && i <= TSTEPS + 1) {
                const int k2 = i - 2;
                uint4 sv[16];
                LOADSPIKES(s2h, (k2 + 1) & 1, sv);         // s2(k2-1)
                float pCl, pCh;
                mv2(WPC, sv, jl, jh, pCl, pCh);
                const float in2l = pBbuf[k2 & 1][jl] + pCl + bi_l;
                const float in2h = pBbuf[k2 & 1][jh] + pCh + bi_h;
                b2_l = r2_l * b2_l + (1.f - r2_l) * s2_l;
                b2_h = r2_h * b2_h + (1.f - r2_h) * s2_h;
                const float Btl = 0.01f + 1.8f * b2_l;
                const float Bth = 0.01f + 1.8f * b2_h;
                h2m_l = h2m_l * a2_l + (1.f - a2_l) * in2l - Btl * s2_l;
                h2m_h = h2m_h * a2_h + (1.f - a2_h) * in2h - Bth * s2_h;
                s2_l = (h2m_l - Btl > 0.f) ? 1.f : 0.f;
                s2_h = (h2m_h - Bth > 0.f) ? 1.f : 0.f;
                s2h[k2 & 1][jl] = (_Float16)s2_l;
                s2h[k2 & 1][jh] = (_Float16)s2_h;
            }
            __syncthreads();
        }
    } else if (w == 3) {
        // ================= RO: rdot(i-3) = W_h2o . s2(i-3) =================
        const int o = lane;
        for (int i = 0; i < TSTEPS + 4; ++i) {
            if (i >= 3 && i <= TSTEPS + 2 && o < ON) {
                const int k3 = i - 3;
                uint4 sv[16];
                LOADSPIKES(s2h, k3 & 1, sv);
                rdot_lds[k3 & 1][o] = mv1(WPO, sv, o);
            }
            __syncthreads();
        }
    } else if (w == 4) {
        // ================= OM: leaky readout + softmax accumulate ==========
        const int o = lane;
        float om = 0.f, ao = 0.f, bo = 0.f, acc = 0.f;
        if (o < ON) {
            om = om0[b * ON + o];
            ao = expf(-1.f / tau_m_o[o]);
            bo = b_h2o[o];
        }
        for (int i = 0; i < TSTEPS + 4; ++i) {
            if (i >= 4) {
                const int k4 = i - 4;
                if (o < ON)
                    om = om * ao + (1.f - ao) * (rdot_lds[k4 & 1][o] + bo);
                float mx = (o < ON) ? om : -3.4e38f;
#pragma unroll
                for (int m = 16; m >= 1; m >>= 1)
                    mx = fmaxf(mx, __shfl_xor(mx, m));
                float e = (o < ON) ? __expf(om - mx) : 0.f;
                float den = e;
#pragma unroll
                for (int m = 16; m >= 1; m >>= 1)
                    den += __shfl_xor(den, m);
                if (o < ON && k4 > 10) acc += e / den;
            }
            __syncthreads();
        }
        if (o < ON) out[b * ON + o] = acc;
    } else {
        // ================= idle waves: barrier balance =================
        for (int i = 0; i < TSTEPS + 4; ++i) __syncthreads();
    }
}

// ---------------------------------------------------------------------------
// Phase C: A_norm = sum|W_h1h1| + sum|W_h2h2|  -> out[5120]  (exact fp32)
// ---------------------------------------------------------------------------
__global__ void anorm_kernel(const float* __restrict__ W1,
                             const float* __restrict__ W2,
                             float* __restrict__ out) {
    __shared__ float red[256];
    float s = 0.f;
    for (int i = threadIdx.x; i < HN * HN; i += 256)
        s += fabsf(W1[i]) + fabsf(W2[i]);
    red[threadIdx.x] = s;
    __syncthreads();
    for (int off = 128; off > 0; off >>= 1) {
        if (threadIdx.x < off) red[threadIdx.x] += red[threadIdx.x + off];
        __syncthreads();
    }
    if (threadIdx.x == 0) out[256 * ON] = red[0];
}

extern "C" void kernel_launch(void* const* d_in, const int* in_sizes, int n_in,
                              void* d_out, int out_size, void* d_ws, size_t ws_size,
                              hipStream_t stream) {
    const float* input      = (const float*)d_in[0];
    // d_in[1], d_in[2]: A1_mask/A2_mask -- all-ones, unused by reference math
    const float* W_ih1      = (const float*)d_in[3];
    const float* b_ih1      = (const float*)d_in[4];
    const float* W_h1h1     = (const float*)d_in[5];
    const float* b_h1h1     = (const float*)d_in[6];
    const float* W_h1h2     = (const float*)d_in[7];
    const float* b_h1h2     = (const float*)d_in[8];
    const float* W_h2h2     = (const float*)d_in[9];
    const float* b_h2h2     = (const float*)d_in[10];
    const float* W_h2o      = (const float*)d_in[11];
    const float* b_h2o      = (const float*)d_in[12];
    const float* tau_adp_h1 = (const float*)d_in[13];
    const float* tau_adp_h2 = (const float*)d_in[14];
    const float* tau_m_h1   = (const float*)d_in[15];
    const float* tau_m_h2   = (const float*)d_in[16];
    const float* tau_m_o    = (const float*)d_in[17];
    const float* h1m0       = (const float*)d_in[18];
    const float* h2m0       = (const float*)d_in[19];
    const float* om0        = (const float*)d_in[20];

    float* out   = (float*)d_out;
    float* ffbuf = (float*)d_ws;   // 256*250*128*4 = 32.768 MB

    anorm_kernel<<<1, 256, 0, stream>>>(W_h1h1, W_h2h2, out);
    ff_gemm<<<500, 256, 0, stream>>>(input, W_ih1, b_ih1, ffbuf);
    srnn_pipe7<<<256, 512, 0, stream>>>(ffbuf, W_h1h1, b_h1h1, W_h1h2, b_h1h2,
                                        W_h2h2, b_h2h2, W_h2o, b_h2o,
                                        tau_adp_h1, tau_adp_h2,
                                        tau_m_h1, tau_m_h2, tau_m_o,
                                        h1m0, h2m0, om0, out);
}

// Round 10
// 347.803 us; speedup vs baseline: 1.3234x; 1.1340x over previous
//
#include <hip/hip_runtime.h>
#include <hip/hip_bf16.h>
#include <stdint.h>

#define HN 128      // hidden size
#define TSTEPS 250
#define ON 20       // output size
#define GK 700      // input size
#define TKK 28      // GEMM K tile (700 = 25*28 exactly)

typedef float v2f __attribute__((ext_vector_type(2)));
typedef _Float16 h2 __attribute__((ext_vector_type(2)));

// VOP3P packed fp32 FMA (GEMM). All sources must be VGPR PAIRS.
__device__ __forceinline__ void pkfma_lo(v2f& acc, v2f b2, v2f a2) {
    asm("v_pk_fma_f32 %0, %1, %2, %0 op_sel_hi:[1,0,1]"
        : "+v"(acc) : "v"(b2), "v"(a2));
}
__device__ __forceinline__ void pkfma_hi(v2f& acc, v2f b2, v2f a2) {
    asm("v_pk_fma_f32 %0, %1, %2, %0 op_sel:[0,1,0] op_sel_hi:[1,1,1]"
        : "+v"(acc) : "v"(b2), "v"(a2));
}

__device__ __forceinline__ h2 bch_u(uint32_t u) { return __builtin_bit_cast(h2, u); }
__device__ __forceinline__ h2 bch_f(float f)    { return __builtin_bit_cast(h2, f); }
__device__ __forceinline__ float fdot2(h2 a, h2 b, float c) {
    return __builtin_amdgcn_fdot2(a, b, c, false);
}
__device__ __forceinline__ float pack2(float x, float y) {
    h2 p; p.x = (_Float16)x; p.y = (_Float16)y;
    return __builtin_bit_cast(float, p);
}

// single-row 128-dot against wave-uniform spike vector sv[16] (128 f16).
// Row j's weights k-major packed: WP[t][j] = w[j][8t..8t+7].
// 16 conflict-free ds_read_b128 + 64 v_dot2 per call.
__device__ __forceinline__ float mv1h(const float4 (&WP)[16][HN],
                                      const uint4 (&sv)[16], int j) {
    float a0 = 0.f, a1 = 0.f, a2 = 0.f, a3 = 0.f;
#pragma unroll
    for (int t = 0; t < 16; ++t) {
        const float4 wl = WP[t][j];
        const uint4  s  = sv[t];
        a0 = fdot2(bch_f(wl.x), bch_u(s.x), a0);
        a1 = fdot2(bch_f(wl.y), bch_u(s.y), a1);
        a2 = fdot2(bch_f(wl.z), bch_u(s.z), a2);
        a3 = fdot2(bch_f(wl.w), bch_u(s.w), a3);
    }
    return (a0 + a1) + (a2 + a3);
}
__device__ __forceinline__ float mv1o(const float4 (&WP)[16][32],
                                      const uint4 (&sv)[16], int j) {
    float a0 = 0.f, a1 = 0.f, a2 = 0.f, a3 = 0.f;
#pragma unroll
    for (int t = 0; t < 16; ++t) {
        const float4 wl = WP[t][j];
        const uint4  s  = sv[t];
        a0 = fdot2(bch_f(wl.x), bch_u(s.x), a0);
        a1 = fdot2(bch_f(wl.y), bch_u(s.y), a1);
        a2 = fdot2(bch_f(wl.z), bch_u(s.z), a2);
        a3 = fdot2(bch_f(wl.w), bch_u(s.w), a3);
    }
    return (a0 + a1) + (a2 + a3);
}

#define LOADSPIKES(arr, buf, sv)                                               \
    {                                                                          \
        const uint4* _p = (const uint4*)&arr[buf][0];                          \
        _Pragma("unroll") for (int _t = 0; _t < 16; ++_t) sv[_t] = _p[_t];     \
    }

// ---------------------------------------------------------------------------
// Phase A: in1_ff[bt,h] = X[bt,:] . W_ih1[h,:] + b_ih1[h]  (fp32, unchanged)
// ---------------------------------------------------------------------------
__global__ __launch_bounds__(256) void ff_gemm(const float* __restrict__ X,
                                               const float* __restrict__ W,
                                               const float* __restrict__ bias,
                                               float* __restrict__ out) {
    __shared__ __align__(16) float Xs[2][TKK][HN];
    __shared__ __align__(16) float Ws[2][TKK][HN];
    const int tid = threadIdx.x;
    const int tx = tid & 15;
    const int ty = tid >> 4;
    const int m0 = blockIdx.x * 128;

    v2f acc2[8][4];
#pragma unroll
    for (int i = 0; i < 8; ++i)
#pragma unroll
        for (int n = 0; n < 4; ++n) acc2[i][n] = (v2f){0.f, 0.f};

    float4 xr[4], wrg[4];

#define LOADT(k0)                                                              \
    {                                                                          \
        _Pragma("unroll")                                                      \
        for (int rr = 0; rr < 4; ++rr) {                                       \
            const int idx = tid + rr * 256;                                    \
            if (idx < 896) {                                                   \
                const int kb = idx >> 7, r = idx & 127;                        \
                xr[rr]  = *(const float4*)&X[(size_t)(m0 + r) * GK + (k0) + kb * 4]; \
                wrg[rr] = *(const float4*)&W[(size_t)r * GK + (k0) + kb * 4];  \
            }                                                                  \
        }                                                                      \
    }
#define STORET(buf)                                                            \
    {                                                                          \
        _Pragma("unroll")                                                      \
        for (int rr = 0; rr < 4; ++rr) {                                       \
            const int idx = tid + rr * 256;                                    \
            if (idx < 896) {                                                   \
                const int kb = idx >> 7, r = idx & 127;                        \
                Xs[buf][kb * 4 + 0][r] = xr[rr].x;                             \
                Xs[buf][kb * 4 + 1][r] = xr[rr].y;                             \
                Xs[buf][kb * 4 + 2][r] = xr[rr].z;                             \
                Xs[buf][kb * 4 + 3][r] = xr[rr].w;                             \
                Ws[buf][kb * 4 + 0][r] = wrg[rr].x;                            \
                Ws[buf][kb * 4 + 1][r] = wrg[rr].y;                            \
                Ws[buf][kb * 4 + 2][r] = wrg[rr].z;                            \
                Ws[buf][kb * 4 + 3][r] = wrg[rr].w;                            \
            }                                                                  \
        }                                                                      \
    }

    LOADT(0);
    STORET(0);
    __syncthreads();
    int cur = 0;
    for (int t = 0; t < 25; ++t) {
        if (t + 1 < 25) LOADT((t + 1) * TKK);
#pragma unroll
        for (int k = 0; k < TKK; ++k) {
            const float4 A0 = *(const float4*)&Xs[cur][k][ty * 8];
            const float4 A1 = *(const float4*)&Xs[cur][k][ty * 8 + 4];
            const float4 B0 = *(const float4*)&Ws[cur][k][tx * 8];
            const float4 B1 = *(const float4*)&Ws[cur][k][tx * 8 + 4];
            v2f a2[4], b2[4];
            a2[0] = (v2f){A0.x, A0.y}; a2[1] = (v2f){A0.z, A0.w};
            a2[2] = (v2f){A1.x, A1.y}; a2[3] = (v2f){A1.z, A1.w};
            b2[0] = (v2f){B0.x, B0.y}; b2[1] = (v2f){B0.z, B0.w};
            b2[2] = (v2f){B1.x, B1.y}; b2[3] = (v2f){B1.z, B1.w};
#pragma unroll
            for (int ip = 0; ip < 4; ++ip)
#pragma unroll
                for (int n = 0; n < 4; ++n) {
                    pkfma_lo(acc2[2 * ip][n],     b2[n], a2[ip]);
                    pkfma_hi(acc2[2 * ip + 1][n], b2[n], a2[ip]);
                }
        }
        if (t + 1 < 25) STORET(cur ^ 1);
        __syncthreads();
        cur ^= 1;
    }

    const float4 bv0 = *(const float4*)&bias[tx * 8];
    const float4 bv1 = *(const float4*)&bias[tx * 8 + 4];
#pragma unroll
    for (int i = 0; i < 8; ++i) {
        const size_t row = (size_t)(m0 + ty * 8 + i);
        float4 v0, v1;
        v0.x = acc2[i][0].x + bv0.x; v0.y = acc2[i][0].y + bv0.y;
        v0.z = acc2[i][1].x + bv0.z; v0.w = acc2[i][1].y + bv0.w;
        v1.x = acc2[i][2].x + bv1.x; v1.y = acc2[i][2].y + bv1.y;
        v1.z = acc2[i][3].x + bv1.z; v1.w = acc2[i][3].y + bv1.w;
        *(float4*)&out[row * HN + tx * 8]     = v0;
        *(float4*)&out[row * HN + tx * 8 + 4] = v1;
    }
#undef LOADT
#undef STORET
}

// ---------------------------------------------------------------------------
// Phase B: f16-LDS dot2 pipeline, 6 heavy waves (all 8 waves working).
// One WG (512 thr, 8 waves) per batch row. Each matvec row-split across 2
// waves, 1 row/lane full-k: 16 weight ds_read_b128 + 16 uniform spike reads
// + 64 v_dot2 per wave -> half the serial chain of r9, 2 heavy waves/SIMD.
// Roles (slot i, one barrier each, r5-verified offsets):
//   w0,w1: S1 -> s1(i)   w2,w3: B -> pB(i-1)   w4,w5: C+L2 -> s2(i-2)
//   w6: RO -> rdot(i-3)  w7: OM -> om/softmax(i-4)
// ---------------------------------------------------------------------------
__global__ __launch_bounds__(512) void srnn_pipe8(
    const float* __restrict__ ff,
    const float* __restrict__ W_h1h1, const float* __restrict__ b_h1h1,
    const float* __restrict__ W_h1h2, const float* __restrict__ b_h1h2,
    const float* __restrict__ W_h2h2, const float* __restrict__ b_h2h2,
    const float* __restrict__ W_h2o,  const float* __restrict__ b_h2o,
    const float* __restrict__ tau_adp_h1, const float* __restrict__ tau_adp_h2,
    const float* __restrict__ tau_m_h1,   const float* __restrict__ tau_m_h2,
    const float* __restrict__ tau_m_o,
    const float* __restrict__ h1m0, const float* __restrict__ h2m0,
    const float* __restrict__ om0,
    float* __restrict__ out) {
    const int b    = blockIdx.x;
    const int tid  = threadIdx.x;
    const int w    = tid >> 6;
    const int lane = tid & 63;

    __shared__ float4 WPA[16][HN];   // 32 KB  W_h1h1 f16 k-major
    __shared__ float4 WPB[16][HN];   // 32 KB  W_h1h2
    __shared__ float4 WPC[16][HN];   // 32 KB  W_h2h2
    __shared__ float4 WPO[16][32];   //  8 KB  W_h2o (rows 0..19, rest zero)
    __shared__ _Float16 s1h[2][HN];
    __shared__ _Float16 s2h[2][HN];
    __shared__ float pBbuf[2][HN];
    __shared__ float rdot_lds[2][32];

    // ---- stage weights fp32->f16 (one time) ----
#pragma unroll
    for (int e = tid; e < 2048; e += 512) {
        const int t = e >> 7, j = e & 127;
        {
            const float* s = W_h1h1 + j * HN + t * 8;
            float4 x0 = *(const float4*)s, x1 = *(const float4*)(s + 4);
            float4 d; d.x = pack2(x0.x, x0.y); d.y = pack2(x0.z, x0.w);
            d.z = pack2(x1.x, x1.y); d.w = pack2(x1.z, x1.w);
            WPA[t][j] = d;
        }
        {
            const float* s = W_h1h2 + j * HN + t * 8;
            float4 x0 = *(const float4*)s, x1 = *(const float4*)(s + 4);
            float4 d; d.x = pack2(x0.x, x0.y); d.y = pack2(x0.z, x0.w);
            d.z = pack2(x1.x, x1.y); d.w = pack2(x1.z, x1.w);
            WPB[t][j] = d;
        }
        {
            const float* s = W_h2h2 + j * HN + t * 8;
            float4 x0 = *(const float4*)s, x1 = *(const float4*)(s + 4);
            float4 d; d.x = pack2(x0.x, x0.y); d.y = pack2(x0.z, x0.w);
            d.z = pack2(x1.x, x1.y); d.w = pack2(x1.z, x1.w);
            WPC[t][j] = d;
        }
    }
    {
        const int t = tid >> 5, j = tid & 31;   // 512 = 16*32 exactly
        float4 d = {0.f, 0.f, 0.f, 0.f};
        if (j < ON) {
            const float* s = W_h2o + j * HN + t * 8;
            float4 x0 = *(const float4*)s, x1 = *(const float4*)(s + 4);
            d.x = pack2(x0.x, x0.y); d.y = pack2(x0.z, x0.w);
            d.z = pack2(x1.x, x1.y); d.w = pack2(x1.z, x1.w);
        }
        WPO[t][j] = d;
    }
    if (tid < HN) {
        s1h[0][tid] = (_Float16)0; s1h[1][tid] = (_Float16)0;
        s2h[0][tid] = (_Float16)0; s2h[1][tid] = (_Float16)0;
    }
    __syncthreads();

    if (w < 2) {
        // ================= S1: layer-1 LIF, j = w*64+lane =================
        const int j = (w << 6) + lane;
        float h1m = h1m0[b * HN + j];
        const float a1 = expf(-1.f / tau_m_h1[j]);
        const float r1 = expf(-1.f / tau_adp_h1[j]);
        const float bi = b_h1h1[j];
        float b1 = 0.01f, s1p = 0.f;
        const float* fp = ff + (size_t)b * TSTEPS * HN + j;
        float fc = fp[0], fn = fp[HN];
        for (int i = 0; i < TSTEPS + 4; ++i) {
            if (i < TSTEPS) {
                const float f2 = (i + 2 < TSTEPS) ? fp[(size_t)(i + 2) * HN] : 0.f;
                uint4 sv[16];
                LOADSPIKES(s1h, (i + 1) & 1, sv);          // s1(i-1)
                const float pA = mv1h(WPA, sv, j);
                b1 = r1 * b1 + (1.f - r1) * s1p;
                const float Bt = 0.01f + 1.8f * b1;
                h1m = h1m * a1 + (1.f - a1) * (fc + bi + pA) - Bt * s1p;
                s1p = (h1m - Bt > 0.f) ? 1.f : 0.f;
                s1h[i & 1][j] = (_Float16)s1p;
                fc = fn; fn = f2;
            }
            __syncthreads();
        }
    } else if (w < 4) {
        // ================= B: pB(i-1) = W_h1h2 . s1(i-1) =================
        const int j = ((w - 2) << 6) + lane;
        for (int i = 0; i < TSTEPS + 4; ++i) {
            if (i >= 1 && i <= TSTEPS) {
                uint4 sv[16];
                LOADSPIKES(s1h, (i - 1) & 1, sv);
                pBbuf[(i - 1) & 1][j] = mv1h(WPB, sv, j);
            }
            __syncthreads();
        }
    } else if (w < 6) {
        // ================= C + LIF2: s2(i-2), j = (w-4)*64+lane ============
        const int j = ((w - 4) << 6) + lane;
        float h2m = h2m0[b * HN + j];
        const float a2 = expf(-1.f / tau_m_h2[j]);
        const float r2 = expf(-1.f / tau_adp_h2[j]);
        const float bi = b_h1h2[j] + b_h2h2[j];
        float b2v = 0.01f, s2p = 0.f;
        for (int i = 0; i < TSTEPS + 4; ++i) {
            if (i >= 2 && i <= TSTEPS + 1) {
                const int k2 = i - 2;
                uint4 sv[16];
                LOADSPIKES(s2h, (k2 + 1) & 1, sv);         // s2(k2-1)
                const float pC = mv1h(WPC, sv, j);
                const float in2 = pBbuf[k2 & 1][j] + pC + bi;
                b2v = r2 * b2v + (1.f - r2) * s2p;
                const float Bt = 0.01f + 1.8f * b2v;
                h2m = h2m * a2 + (1.f - a2) * in2 - Bt * s2p;
                s2p = (h2m - Bt > 0.f) ? 1.f : 0.f;
                s2h[k2 & 1][j] = (_Float16)s2p;
            }
            __syncthreads();
        }
    } else if (w == 6) {
        // ================= RO: rdot(i-3) = W_h2o . s2(i-3) =================
        const int o = lane;
        for (int i = 0; i < TSTEPS + 4; ++i) {
            if (i >= 3 && i <= TSTEPS + 2 && o < ON) {
                const int k3 = i - 3;
                uint4 sv[16];
                LOADSPIKES(s2h, k3 & 1, sv);
                rdot_lds[k3 & 1][o] = mv1o(WPO, sv, o);
            }
            __syncthreads();
        }
    } else {
        // ================= OM: leaky readout + softmax accumulate ==========
        const int o = lane;
        float om = 0.f, ao = 0.f, bo = 0.f, acc = 0.f;
        if (o < ON) {
            om = om0[b * ON + o];
            ao = expf(-1.f / tau_m_o[o]);
            bo = b_h2o[o];
        }
        for (int i = 0; i < TSTEPS + 4; ++i) {
            if (i >= 4) {
                const int k4 = i - 4;
                if (o < ON)
                    om = om * ao + (1.f - ao) * (rdot_lds[k4 & 1][o] + bo);
                float mx = (o < ON) ? om : -3.4e38f;
#pragma unroll
                for (int m = 16; m >= 1; m >>= 1)
                    mx = fmaxf(mx, __shfl_xor(mx, m));
                float e = (o < ON) ? __expf(om - mx) : 0.f;
                float den = e;
#pragma unroll
                for (int m = 16; m >= 1; m >>= 1)
                    den += __shfl_xor(den, m);
                if (o < ON && k4 > 10) acc += e / den;
            }
            __syncthreads();
        }
        if (o < ON) out[b * ON + o] = acc;
    }
}

// ---------------------------------------------------------------------------
// Phase C: A_norm = sum|W_h1h1| + sum|W_h2h2|  -> out[5120]  (exact fp32)
// ---------------------------------------------------------------------------
__global__ void anorm_kernel(const float* __restrict__ W1,
                             const float* __restrict__ W2,
                             float* __restrict__ out) {
    __shared__ float red[256];
    float s = 0.f;
    for (int i = threadIdx.x; i < HN * HN; i += 256)
        s += fabsf(W1[i]) + fabsf(W2[i]);
    red[threadIdx.x] = s;
    __syncthreads();
    for (int off = 128; off > 0; off >>= 1) {
        if (threadIdx.x < off) red[threadIdx.x] += red[threadIdx.x + off];
        __syncthreads();
    }
    if (threadIdx.x == 0) out[256 * ON] = red[0];
}

extern "C" void kernel_launch(void* const* d_in, const int* in_sizes, int n_in,
                              void* d_out, int out_size, void* d_ws, size_t ws_size,
                              hipStream_t stream) {
    const float* input      = (const float*)d_in[0];
    // d_in[1], d_in[2]: A1_mask/A2_mask -- all-ones, unused by reference math
    const float* W_ih1      = (const float*)d_in[3];
    const float* b_ih1      = (const float*)d_in[4];
    const float* W_h1h1     = (const float*)d_in[5];
    const float* b_h1h1     = (const float*)d_in[6];
    const float* W_h1h2     = (const float*)d_in[7];
    const float* b_h1h2     = (const float*)d_in[8];
    const float* W_h2h2     = (const float*)d_in[9];
    const float* b_h2h2     = (const float*)d_in[10];
    const float* W_h2o      = (const float*)d_in[11];
    const float* b_h2o      = (const float*)d_in[12];
    const float* tau_adp_h1 = (const float*)d_in[13];
    const float* tau_adp_h2 = (const float*)d_in[14];
    const float* tau_m_h1   = (const float*)d_in[15];
    const float* tau_m_h2   = (const float*)d_in[16];
    const float* tau_m_o    = (const float*)d_in[17];
    const float* h1m0       = (const float*)d_in[18];
    const float* h2m0       = (const float*)d_in[19];
    const float* om0        = (const float*)d_in[20];

    float* out   = (float*)d_out;
    float* ffbuf = (float*)d_ws;   // 256*250*128*4 = 32.768 MB

    anorm_kernel<<<1, 256, 0, stream>>>(W_h1h1, W_h2h2, out);
    ff_gemm<<<500, 256, 0, stream>>>(input, W_ih1, b_ih1, ffbuf);
    srnn_pipe8<<<256, 512, 0, stream>>>(ffbuf, W_h1h1, b_h1h1, W_h1h2, b_h1h2,
                                        W_h2h2, b_h2h2, W_h2o, b_h2o,
                                        tau_adp_h1, tau_adp_h2,
                                        tau_m_h1, tau_m_h2, tau_m_o,
                                        h1m0, h2m0, om0, out);
}